// Round 3
// baseline (1161.429 us; speedup 1.0000x reference)
//
#include <hip/hip_runtime.h>

#define U_CNT 100000
#define I_CNT 50000
#define N_CNT 150000
#define D_CNT 64
#define NNZ_CNT 1000000

#define OFF_ITEM   6400000LL
#define OFF_STACK  9600000LL
#define OFF_PATH   48000000LL

#define RPB   64      // rows per bucket
#define ASTRIDE 65    // padded LDS row stride (floats) -> bank spread for ds_add
#define NBUK  2344    // ceil(150000/64)
#define EPB   8192    // edges per block in build kernels
#define NBLD  123     // ceil(NNZ/EPB)
#define UNR   8       // edge unroll depth (MLP) in bspmm

// ---------------- bucket-CSR build ----------------

__global__ void bzero_k(int* __restrict__ cnt) {
    int i = blockIdx.x * blockDim.x + threadIdx.x;
    if (i < 2 * NBUK) cnt[i] = 0;
}

// LDS-privatized bucket histogram; 8-deep batched loads for MLP.
__global__ __launch_bounds__(256) void bhist_k(const int* __restrict__ arows,
                                               const int* __restrict__ rrows,
                                               int* __restrict__ cnt) {
    __shared__ int h[NBUK];
    for (int i = threadIdx.x; i < NBUK; i += 256) h[i] = 0;
    __syncthreads();
    const int* rows = blockIdx.y ? rrows : arows;
    int base = blockIdx.x * EPB;
    int t = threadIdx.x;
    if (base + EPB <= NNZ_CNT) {
        #pragma unroll
        for (int g = 0; g < EPB / (256 * 8); ++g) {
            int r[8];
            #pragma unroll
            for (int k = 0; k < 8; ++k)
                r[k] = rows[base + (g * 8 + k) * 256 + t];
            #pragma unroll
            for (int k = 0; k < 8; ++k)
                atomicAdd(&h[r[k] >> 6], 1);
        }
    } else {
        for (int i = base + t; i < NNZ_CNT; i += 256)
            atomicAdd(&h[rows[i] >> 6], 1);
    }
    __syncthreads();
    int* c = cnt + blockIdx.y * NBUK;
    for (int i = threadIdx.x; i < NBUK; i += 256) {
        int v = h[i];
        if (v) atomicAdd(&c[i], v);
    }
}

// exclusive scan of NBUK counts per array; one block per array (blockIdx.x).
__global__ __launch_bounds__(1024) void bscan_k(const int* __restrict__ cnt,
                                                int* __restrict__ off,
                                                int* __restrict__ cur) {
    __shared__ int s[1024];
    const int* c = cnt + blockIdx.x * NBUK;
    int t = threadIdx.x;
    int v[3];
    int run = 0;
    int base = t * 3;
    #pragma unroll
    for (int k = 0; k < 3; ++k) {
        v[k] = (base + k < NBUK) ? c[base + k] : 0;
        run += v[k];
    }
    s[t] = run;
    __syncthreads();
    for (int d = 1; d < 1024; d <<= 1) {
        int a = (t >= d) ? s[t - d] : 0;
        __syncthreads();
        s[t] += a;
        __syncthreads();
    }
    int pre = (t > 0) ? s[t - 1] : 0;
    int* o = off + blockIdx.x * NBUK;
    int* u = cur + blockIdx.x * NBUK;
    #pragma unroll
    for (int k = 0; k < 3; ++k) {
        if (base + k < NBUK) { o[base + k] = pre; u[base + k] = pre; }
        pre += v[k];
    }
}

// scatter edges into bucket-grouped order; per-(block,bucket) chunk reservation.
// Both passes 8-deep batched for MLP.
__global__ __launch_bounds__(256) void bscat_k(
    const int* __restrict__ arows, const int* __restrict__ acols, const float* __restrict__ avals,
    const int* __restrict__ rrows, const int* __restrict__ rcols, const float* __restrict__ rvals,
    int* __restrict__ cur, int2* __restrict__ ed) {
    __shared__ int h[NBUK];
    const int*   rows = blockIdx.y ? rrows : arows;
    const int*   cols = blockIdx.y ? rcols : acols;
    const float* vals = blockIdx.y ? rvals : avals;
    int*  c = cur + blockIdx.y * NBUK;
    int2* e = ed + (size_t)blockIdx.y * NNZ_CNT;
    int t = threadIdx.x;
    for (int i = t; i < NBUK; i += 256) h[i] = 0;
    __syncthreads();
    int base = blockIdx.x * EPB;
    bool full = (base + EPB <= NNZ_CNT);
    if (full) {
        #pragma unroll
        for (int g = 0; g < EPB / (256 * 8); ++g) {
            int r[8];
            #pragma unroll
            for (int k = 0; k < 8; ++k)
                r[k] = rows[base + (g * 8 + k) * 256 + t];
            #pragma unroll
            for (int k = 0; k < 8; ++k)
                atomicAdd(&h[r[k] >> 6], 1);
        }
    } else {
        for (int i = base + t; i < NNZ_CNT; i += 256)
            atomicAdd(&h[rows[i] >> 6], 1);
    }
    __syncthreads();
    for (int i = t; i < NBUK; i += 256) {
        int n = h[i];
        h[i] = n ? atomicAdd(&c[i], n) : 0;   // h[b] becomes running global cursor
    }
    __syncthreads();
    if (full) {
        #pragma unroll
        for (int g = 0; g < EPB / (256 * 8); ++g) {
            int r[8], cc[8]; float vv[8];
            #pragma unroll
            for (int k = 0; k < 8; ++k) {
                int i = base + (g * 8 + k) * 256 + t;
                r[k] = rows[i]; cc[k] = cols[i]; vv[k] = vals[i];
            }
            #pragma unroll
            for (int k = 0; k < 8; ++k) {
                int pos = atomicAdd(&h[r[k] >> 6], 1);
                e[pos] = make_int2(((r[k] & 63) << 18) | cc[k], __float_as_int(vv[k]));
            }
        }
    } else {
        for (int i = base + t; i < NNZ_CNT; i += 256) {
            int r = rows[i];
            int pos = atomicAdd(&h[r >> 6], 1);
            e[pos] = make_int2(((r & 63) << 18) | cols[i], __float_as_int(vals[i]));
        }
    }
}

// block per bucket: 256 threads = 16 edge-slots x 16 float4-lanes, 8 edges deep
// per iteration. Batched loads -> up to 8 independent row gathers in flight
// per thread (the round-2 kernel had MLP=1: ev->x->ds_add serialized).
__global__ __launch_bounds__(256) void bspmm_k(
    const int* __restrict__ off, const int* __restrict__ cnt,
    const int2* __restrict__ ed,
    const float* __restrict__ user_emb, const float* __restrict__ item_emb,
    float* __restrict__ out) {
    __shared__ float acc[RPB * ASTRIDE];  // 16.64 KB
    int which = blockIdx.y;
    int b = blockIdx.x;
    const int2* e = ed + (size_t)which * NNZ_CNT;
    int o = off[which * NBUK + b];
    int c = cnt[which * NBUK + b];
    int t = threadIdx.x;
    int s = t >> 4;   // edge slot 0..15
    int q = t & 15;   // float4 slot (dim quarter)
    for (int i = t; i < RPB * ASTRIDE; i += 256) acc[i] = 0.f;
    __syncthreads();
    for (int base = 0; base < c; base += 16 * UNR) {
        int2 ev[UNR];
        #pragma unroll
        for (int k = 0; k < UNR; ++k) {
            int idx = base + k * 16 + s;
            ev[k] = (idx < c) ? e[o + idx] : make_int2(0, 0);  // v=0 -> adds 0
        }
        float4 x[UNR];
        int rl[UNR];
        float v[UNR];
        #pragma unroll
        for (int k = 0; k < UNR; ++k) {
            int pack = ev[k].x;
            v[k] = __int_as_float(ev[k].y);
            int col = pack & 0x3FFFF;
            rl[k] = pack >> 18;
            const float* src = (col < U_CNT) ? (user_emb + (size_t)col * D_CNT)
                                             : (item_emb + (size_t)(col - U_CNT) * D_CNT);
            x[k] = *(const float4*)(src + q * 4);
        }
        #pragma unroll
        for (int k = 0; k < UNR; ++k) {
            float* a = &acc[rl[k] * ASTRIDE + q * 4];
            __hip_atomic_fetch_add(a + 0, v[k] * x[k].x, __ATOMIC_RELAXED, __HIP_MEMORY_SCOPE_WORKGROUP);
            __hip_atomic_fetch_add(a + 1, v[k] * x[k].y, __ATOMIC_RELAXED, __HIP_MEMORY_SCOPE_WORKGROUP);
            __hip_atomic_fetch_add(a + 2, v[k] * x[k].z, __ATOMIC_RELAXED, __HIP_MEMORY_SCOPE_WORKGROUP);
            __hip_atomic_fetch_add(a + 3, v[k] * x[k].w, __ATOMIC_RELAXED, __HIP_MEMORY_SCOPE_WORKGROUP);
        }
    }
    __syncthreads();
    // epilogue: each wave writes 16 rows (ego, acc x3, optional mean)
    int wid = t >> 6, lane = t & 63;
    for (int rl2 = wid * 16; rl2 < wid * 16 + 16; ++rl2) {
        int row = b * RPB + rl2;
        if (row >= N_CNT) break;
        float a = acc[rl2 * ASTRIDE + lane];
        const float* esrc = (row < U_CNT) ? (user_emb + (size_t)row * D_CNT)
                                          : (item_emb + (size_t)(row - U_CNT) * D_CNT);
        float eg = esrc[lane];
        long long rb = (which ? OFF_PATH : OFF_STACK) + (long long)row * 256;
        out[rb + lane]       = eg;
        out[rb + 64 + lane]  = a;
        out[rb + 128 + lane] = a;
        out[rb + 192 + lane] = a;
        if (which == 0) {
            float mv = 0.25f * eg + 0.75f * a;
            long long mb = (row < U_CNT) ? (long long)row * D_CNT
                                         : OFF_ITEM + (long long)(row - U_CNT) * D_CNT;
            out[mb + lane] = mv;
        }
    }
}

// ---------------- fallback atomic path (ws too small) ----------------

__global__ void zero_slot1_k(float* __restrict__ out) {
    int t = blockIdx.x * blockDim.x + threadIdx.x;
    if (t >= N_CNT * 16) return;
    int n = t >> 4, q = t & 15;
    long long off = (long long)n * 256 + 64 + (long long)q * 4;
    float4 z = make_float4(0.f, 0.f, 0.f, 0.f);
    *(float4*)(out + OFF_STACK + off) = z;
    *(float4*)(out + OFF_PATH  + off) = z;
}

__global__ void scatter_fb_k(const int* __restrict__ rows, const int* __restrict__ cols,
                             const float* __restrict__ vals,
                             const float* __restrict__ user_emb, const float* __restrict__ item_emb,
                             float* __restrict__ acc) {
    long long t = (long long)blockIdx.x * blockDim.x + threadIdx.x;
    int e = (int)(t >> 4);
    if (e >= NNZ_CNT) return;
    int q = (int)(t & 15);
    int r = rows[e];
    int c = cols[e];
    float v = vals[e];
    const float* src = (c < U_CNT) ? (user_emb + (long long)c * D_CNT)
                                   : (item_emb + (long long)(c - U_CNT) * D_CNT);
    float4 x = *(const float4*)(src + q * 4);
    float* dst = acc + (long long)r * 256 + q * 4;
    atomicAdd(dst + 0, v * x.x);
    atomicAdd(dst + 1, v * x.y);
    atomicAdd(dst + 2, v * x.z);
    atomicAdd(dst + 3, v * x.w);
}

__global__ void finalize_k(const float* __restrict__ user_emb,
                           const float* __restrict__ item_emb,
                           float* __restrict__ out) {
    int t = blockIdx.x * blockDim.x + threadIdx.x;
    if (t >= N_CNT * 16) return;
    int n = t >> 4, q = t & 15;
    const float* src = (n < U_CNT) ? (user_emb + (long long)n * D_CNT)
                                   : (item_emb + (long long)(n - U_CNT) * D_CNT);
    float4 e4 = *(const float4*)(src + q * 4);
    float* st = out + OFF_STACK + (long long)n * 256;
    float* pt = out + OFF_PATH  + (long long)n * 256;
    float4 a4 = *(const float4*)(st + 64 + q * 4);
    float4 r4 = *(const float4*)(pt + 64 + q * 4);
    float4 m4 = make_float4(0.25f * e4.x + 0.75f * a4.x, 0.25f * e4.y + 0.75f * a4.y,
                            0.25f * e4.z + 0.75f * a4.z, 0.25f * e4.w + 0.75f * a4.w);
    *(float4*)(st + q * 4)       = e4;
    *(float4*)(st + 128 + q * 4) = a4;
    *(float4*)(st + 192 + q * 4) = a4;
    *(float4*)(pt + q * 4)       = e4;
    *(float4*)(pt + 128 + q * 4) = r4;
    *(float4*)(pt + 192 + q * 4) = r4;
    float* md = (n < U_CNT) ? (out + (long long)n * D_CNT)
                            : (out + OFF_ITEM + (long long)(n - U_CNT) * D_CNT);
    *(float4*)(md + q * 4) = m4;
}

extern "C" void kernel_launch(void* const* d_in, const int* in_sizes, int n_in,
                              void* d_out, int out_size, void* d_ws, size_t ws_size,
                              hipStream_t stream) {
    const float* user_emb  = (const float*)d_in[0];
    const float* item_emb  = (const float*)d_in[1];
    const int*   adj_rows  = (const int*)d_in[2];
    const int*   adj_cols  = (const int*)d_in[3];
    const float* adj_vals  = (const float*)d_in[4];
    const int*   radj_rows = (const int*)d_in[5];
    const int*   radj_cols = (const int*)d_in[6];
    const float* radj_vals = (const float*)d_in[7];
    float* out = (float*)d_out;
    const int BLK = 256;

    // ws layout (ints): cnt[2*NBUK], off[2*NBUK], cur[2*NBUK], then int2 ed[2*NNZ]
    size_t need = (size_t)(6 * NBUK) * 4 + (size_t)2 * NNZ_CNT * 8;
    if (ws_size >= need) {
        int* cnt = (int*)d_ws;
        int* off = cnt + 2 * NBUK;
        int* cur = off + 2 * NBUK;
        int2* ed = (int2*)(cur + 2 * NBUK);

        bzero_k<<<(2 * NBUK + BLK - 1) / BLK, BLK, 0, stream>>>(cnt);
        bhist_k<<<dim3(NBLD, 2), 256, 0, stream>>>(adj_rows, radj_rows, cnt);
        bscan_k<<<2, 1024, 0, stream>>>(cnt, off, cur);
        bscat_k<<<dim3(NBLD, 2), 256, 0, stream>>>(adj_rows, adj_cols, adj_vals,
                                                   radj_rows, radj_cols, radj_vals,
                                                   cur, ed);
        bspmm_k<<<dim3(NBUK, 2), 256, 0, stream>>>(off, cnt, ed, user_emb, item_emb, out);
    } else {
        int zgrid = (N_CNT * 16 + BLK - 1) / BLK;
        int sgrid = (int)(((long long)NNZ_CNT * 16 + BLK - 1) / BLK);
        zero_slot1_k<<<zgrid, BLK, 0, stream>>>(out);
        scatter_fb_k<<<sgrid, BLK, 0, stream>>>(adj_rows, adj_cols, adj_vals,
                                                user_emb, item_emb, out + OFF_STACK + 64);
        scatter_fb_k<<<sgrid, BLK, 0, stream>>>(radj_rows, radj_cols, radj_vals,
                                                user_emb, item_emb, out + OFF_PATH + 64);
        finalize_k<<<zgrid, BLK, 0, stream>>>(user_emb, item_emb, out);
    }
}

// Round 4
// 683.897 us; speedup vs baseline: 1.6983x; 1.6983x over previous
//
#include <hip/hip_runtime.h>

#define U_CNT 100000
#define I_CNT 50000
#define N_CNT 150000
#define D_CNT 64
#define NNZ_CNT 1000000

#define OFF_ITEM   6400000LL
#define OFF_STACK  9600000LL
#define OFF_PATH   48000000LL

#define RPB   64      // rows per bucket
#define NBUK  2344    // ceil(150000/64)
#define SP    32      // counter pad stride (ints) -> 1 cache line per counter
#define CAP   1024    // edges per bspmm chunk
#define EBUF  1536    // CAP + 64*7 pad slots (row runs padded to multiple of 8)

// ---------------- bucket-CSR build (global-atomic, full occupancy) ----------------

__global__ void bzero_k(int* __restrict__ cnt_p) {
    int i = blockIdx.x * blockDim.x + threadIdx.x;
    if (i < 2 * NBUK * SP) cnt_p[i] = 0;
}

// 250K threads, int4 loads, 4 independent global atomics each (MLP=4).
__global__ __launch_bounds__(256) void bhist_k(const int* __restrict__ arows,
                                               const int* __restrict__ rrows,
                                               int* __restrict__ cnt_p) {
    int gid = blockIdx.x * 256 + threadIdx.x;
    if (gid >= NNZ_CNT / 4) return;
    const int4* rows = (const int4*)(blockIdx.y ? rrows : arows);
    int* c = cnt_p + (size_t)blockIdx.y * NBUK * SP;
    int4 r = rows[gid];
    atomicAdd(&c[(r.x >> 6) * SP], 1);
    atomicAdd(&c[(r.y >> 6) * SP], 1);
    atomicAdd(&c[(r.z >> 6) * SP], 1);
    atomicAdd(&c[(r.w >> 6) * SP], 1);
}

// exclusive scan of NBUK padded counters per matrix; one block per matrix.
__global__ __launch_bounds__(1024) void bscan_k(const int* __restrict__ cnt_p,
                                                int* __restrict__ off,
                                                int* __restrict__ cur_p) {
    __shared__ int s[1024];
    const int m = blockIdx.x;
    const int t = threadIdx.x;
    int v[3];
    int run = 0;
    int base = t * 3;
    #pragma unroll
    for (int k = 0; k < 3; ++k) {
        v[k] = (base + k < NBUK) ? cnt_p[(m * NBUK + base + k) * SP] : 0;
        run += v[k];
    }
    s[t] = run;
    __syncthreads();
    for (int d = 1; d < 1024; d <<= 1) {
        int a = (t >= d) ? s[t - d] : 0;
        __syncthreads();
        s[t] += a;
        __syncthreads();
    }
    int pre = (t > 0) ? s[t - 1] : 0;
    #pragma unroll
    for (int k = 0; k < 3; ++k) {
        if (base + k < NBUK) {
            off[m * NBUK + base + k] = pre;
            cur_p[(m * NBUK + base + k) * SP] = pre;
        }
        pre += v[k];
    }
}

// one-pass scatter: int4 loads, 4 independent pos-atomics, 4 int2 stores.
__global__ __launch_bounds__(256) void bscat_k(
    const int* __restrict__ arows, const int* __restrict__ acols, const float* __restrict__ avals,
    const int* __restrict__ rrows, const int* __restrict__ rcols, const float* __restrict__ rvals,
    int* __restrict__ cur_p, int2* __restrict__ ed) {
    int gid = blockIdx.x * 256 + threadIdx.x;
    if (gid >= NNZ_CNT / 4) return;
    const int4*   rows = (const int4*)(blockIdx.y ? rrows : arows);
    const int4*   cols = (const int4*)(blockIdx.y ? rcols : acols);
    const float4* vals = (const float4*)(blockIdx.y ? rvals : avals);
    int*  cu = cur_p + (size_t)blockIdx.y * NBUK * SP;
    int2* e  = ed + (size_t)blockIdx.y * NNZ_CNT;
    int4 r = rows[gid];
    int4 c = cols[gid];
    float4 v = vals[gid];
    int p0 = atomicAdd(&cu[(r.x >> 6) * SP], 1);
    int p1 = atomicAdd(&cu[(r.y >> 6) * SP], 1);
    int p2 = atomicAdd(&cu[(r.z >> 6) * SP], 1);
    int p3 = atomicAdd(&cu[(r.w >> 6) * SP], 1);
    e[p0] = make_int2(((r.x & 63) << 18) | c.x, __float_as_int(v.x));
    e[p1] = make_int2(((r.y & 63) << 18) | c.y, __float_as_int(v.y));
    e[p2] = make_int2(((r.z & 63) << 18) | c.z, __float_as_int(v.z));
    e[p3] = make_int2(((r.w & 63) << 18) | c.w, __float_as_int(v.w));
}

// block per bucket: sort the bucket's edges by row in LDS (64-bin counting sort,
// int LDS atomics only), rows padded to multiples of 8 with zero-edges. Then each
// wave owns 16 rows exclusively: per row, a single register accumulator, inner
// loop = 8 uniform LDS broadcasts -> 8 independent 256B row gathers -> 8 FMAs.
// NO float atomics anywhere (rounds 1-3 serialized on slow LDS float RMW).
__global__ __launch_bounds__(256) void bspmm_k(
    const int* __restrict__ off, const int* __restrict__ cnt_p,
    const int2* __restrict__ ed,
    const float* __restrict__ user_emb, const float* __restrict__ item_emb,
    float* __restrict__ out) {
    __shared__ int2 ebuf[EBUF];
    __shared__ int rcnt[64];
    __shared__ int rcur[64];
    __shared__ int roff[65];
    const int which = blockIdx.y;
    const int b = blockIdx.x;
    const int2* e = ed + (size_t)which * NNZ_CNT;
    const int o = off[which * NBUK + b];
    const int c = cnt_p[(which * NBUK + b) * SP];
    const int t = threadIdx.x, wid = t >> 6, lane = t & 63;
    const bool multi = (c > CAP);
    const int nchunk = multi ? (c + CAP - 1) / CAP : 1;

    for (int ci = 0; ci < nchunk; ++ci) {
        const int s = ci * CAP;
        int cc = c - s;
        if (cc > CAP) cc = CAP;
        if (cc < 0) cc = 0;
        for (int i = t; i < EBUF; i += 256) ebuf[i] = make_int2(0, 0);
        if (t < 64) rcnt[t] = 0;
        __syncthreads();
        int2 er[4];
        #pragma unroll
        for (int k = 0; k < 4; ++k) {
            int i = t + k * 256;
            er[k] = (i < cc) ? e[o + s + i] : make_int2(-1, 0);
        }
        #pragma unroll
        for (int k = 0; k < 4; ++k)
            if (er[k].x >= 0) atomicAdd(&rcnt[er[k].x >> 18], 1);
        __syncthreads();
        if (t < 64) {
            int pv = (rcnt[t] + 7) & ~7;     // pad row run to multiple of 8
            int incl = pv;
            #pragma unroll
            for (int d = 1; d < 64; d <<= 1) {
                int u = __shfl_up(incl, d);
                if (lane >= d) incl += u;
            }
            roff[t + 1] = incl;
            if (t == 0) roff[0] = 0;
            rcur[t] = incl - pv;
        }
        __syncthreads();
        #pragma unroll
        for (int k = 0; k < 4; ++k)
            if (er[k].x >= 0) {
                int p = atomicAdd(&rcur[er[k].x >> 18], 1);
                ebuf[p] = er[k];
            }
        __syncthreads();
        // each wave processes its 16 rows with register accumulation
        for (int rr = 0; rr < 16; ++rr) {
            const int r = wid * 16 + rr;
            const int row = b * RPB + r;
            const int j0 = roff[r], j1 = roff[r + 1];
            float acc = 0.f;
            for (int j = j0; j < j1; j += 8) {
                float g[8], vv[8];
                #pragma unroll
                for (int k = 0; k < 8; ++k) {
                    int2 E = ebuf[j + k];                 // uniform addr -> LDS broadcast
                    int col = E.x & 0x3FFFF;              // pad edges: col=0, v=0
                    const float* src = (col < U_CNT) ? (user_emb + (size_t)col * D_CNT)
                                                     : (item_emb + (size_t)(col - U_CNT) * D_CNT);
                    g[k] = src[lane];
                    vv[k] = __int_as_float(E.y);
                }
                #pragma unroll
                for (int k = 0; k < 8; ++k) acc = fmaf(vv[k], g[k], acc);
            }
            if (row < N_CNT) {
                const long long rb = (which ? OFF_PATH : OFF_STACK) + (long long)row * 256;
                if (!multi) {
                    const float* esrc = (row < U_CNT) ? (user_emb + (size_t)row * D_CNT)
                                                      : (item_emb + (size_t)(row - U_CNT) * D_CNT);
                    float eg = esrc[lane];
                    out[rb + lane]       = eg;
                    out[rb + 64 + lane]  = acc;
                    out[rb + 128 + lane] = acc;
                    out[rb + 192 + lane] = acc;
                    if (which == 0) {
                        float mv = 0.25f * eg + 0.75f * acc;
                        long long mb = (row < U_CNT) ? (long long)row * D_CNT
                                                     : OFF_ITEM + (long long)(row - U_CNT) * D_CNT;
                        out[mb + lane] = mv;
                    }
                } else {
                    float prev = (ci == 0) ? 0.f : out[rb + 64 + lane];
                    out[rb + 64 + lane] = prev + acc;
                }
            }
        }
        __syncthreads();
    }
    if (multi) {
        for (int rr = 0; rr < 16; ++rr) {
            const int r = wid * 16 + rr;
            const int row = b * RPB + r;
            if (row >= N_CNT) continue;
            const long long rb = (which ? OFF_PATH : OFF_STACK) + (long long)row * 256;
            float acc = out[rb + 64 + lane];
            const float* esrc = (row < U_CNT) ? (user_emb + (size_t)row * D_CNT)
                                              : (item_emb + (size_t)(row - U_CNT) * D_CNT);
            float eg = esrc[lane];
            out[rb + lane]       = eg;
            out[rb + 128 + lane] = acc;
            out[rb + 192 + lane] = acc;
            if (which == 0) {
                float mv = 0.25f * eg + 0.75f * acc;
                long long mb = (row < U_CNT) ? (long long)row * D_CNT
                                             : OFF_ITEM + (long long)(row - U_CNT) * D_CNT;
                out[mb + lane] = mv;
            }
        }
    }
}

// ---------------- fallback atomic path (ws too small) ----------------

__global__ void zero_slot1_k(float* __restrict__ out) {
    int t = blockIdx.x * blockDim.x + threadIdx.x;
    if (t >= N_CNT * 16) return;
    int n = t >> 4, q = t & 15;
    long long off = (long long)n * 256 + 64 + (long long)q * 4;
    float4 z = make_float4(0.f, 0.f, 0.f, 0.f);
    *(float4*)(out + OFF_STACK + off) = z;
    *(float4*)(out + OFF_PATH  + off) = z;
}

__global__ void scatter_fb_k(const int* __restrict__ rows, const int* __restrict__ cols,
                             const float* __restrict__ vals,
                             const float* __restrict__ user_emb, const float* __restrict__ item_emb,
                             float* __restrict__ acc) {
    long long t = (long long)blockIdx.x * blockDim.x + threadIdx.x;
    int e = (int)(t >> 4);
    if (e >= NNZ_CNT) return;
    int q = (int)(t & 15);
    int r = rows[e];
    int c = cols[e];
    float v = vals[e];
    const float* src = (c < U_CNT) ? (user_emb + (long long)c * D_CNT)
                                   : (item_emb + (long long)(c - U_CNT) * D_CNT);
    float4 x = *(const float4*)(src + q * 4);
    float* dst = acc + (long long)r * 256 + q * 4;
    atomicAdd(dst + 0, v * x.x);
    atomicAdd(dst + 1, v * x.y);
    atomicAdd(dst + 2, v * x.z);
    atomicAdd(dst + 3, v * x.w);
}

__global__ void finalize_k(const float* __restrict__ user_emb,
                           const float* __restrict__ item_emb,
                           float* __restrict__ out) {
    int t = blockIdx.x * blockDim.x + threadIdx.x;
    if (t >= N_CNT * 16) return;
    int n = t >> 4, q = t & 15;
    const float* src = (n < U_CNT) ? (user_emb + (long long)n * D_CNT)
                                   : (item_emb + (long long)(n - U_CNT) * D_CNT);
    float4 e4 = *(const float4*)(src + q * 4);
    float* st = out + OFF_STACK + (long long)n * 256;
    float* pt = out + OFF_PATH  + (long long)n * 256;
    float4 a4 = *(const float4*)(st + 64 + q * 4);
    float4 r4 = *(const float4*)(pt + 64 + q * 4);
    float4 m4 = make_float4(0.25f * e4.x + 0.75f * a4.x, 0.25f * e4.y + 0.75f * a4.y,
                            0.25f * e4.z + 0.75f * a4.z, 0.25f * e4.w + 0.75f * a4.w);
    *(float4*)(st + q * 4)       = e4;
    *(float4*)(st + 128 + q * 4) = a4;
    *(float4*)(st + 192 + q * 4) = a4;
    *(float4*)(pt + q * 4)       = e4;
    *(float4*)(pt + 128 + q * 4) = r4;
    *(float4*)(pt + 192 + q * 4) = r4;
    float* md = (n < U_CNT) ? (out + (long long)n * D_CNT)
                            : (out + OFF_ITEM + (long long)(n - U_CNT) * D_CNT);
    *(float4*)(md + q * 4) = m4;
}

extern "C" void kernel_launch(void* const* d_in, const int* in_sizes, int n_in,
                              void* d_out, int out_size, void* d_ws, size_t ws_size,
                              hipStream_t stream) {
    const float* user_emb  = (const float*)d_in[0];
    const float* item_emb  = (const float*)d_in[1];
    const int*   adj_rows  = (const int*)d_in[2];
    const int*   adj_cols  = (const int*)d_in[3];
    const float* adj_vals  = (const float*)d_in[4];
    const int*   radj_rows = (const int*)d_in[5];
    const int*   radj_cols = (const int*)d_in[6];
    const float* radj_vals = (const float*)d_in[7];
    float* out = (float*)d_out;
    const int BLK = 256;

    // ws layout (ints): cnt_p[2*NBUK*SP], cur_p[2*NBUK*SP], off[2*NBUK], then int2 ed[2*NNZ]
    size_t need = ((size_t)4 * NBUK * SP + 2 * NBUK) * 4 + (size_t)2 * NNZ_CNT * 8;
    if (ws_size >= need) {
        int* cnt_p = (int*)d_ws;
        int* cur_p = cnt_p + 2 * NBUK * SP;
        int* off   = cur_p + 2 * NBUK * SP;
        int2* ed   = (int2*)(off + 2 * NBUK);

        bzero_k<<<(2 * NBUK * SP + BLK - 1) / BLK, BLK, 0, stream>>>(cnt_p);
        int vgrid = (NNZ_CNT / 4 + 255) / 256;
        bhist_k<<<dim3(vgrid, 2), 256, 0, stream>>>(adj_rows, radj_rows, cnt_p);
        bscan_k<<<2, 1024, 0, stream>>>(cnt_p, off, cur_p);
        bscat_k<<<dim3(vgrid, 2), 256, 0, stream>>>(adj_rows, adj_cols, adj_vals,
                                                    radj_rows, radj_cols, radj_vals,
                                                    cur_p, ed);
        bspmm_k<<<dim3(NBUK, 2), 256, 0, stream>>>(off, cnt_p, ed, user_emb, item_emb, out);
    } else {
        int zgrid = (N_CNT * 16 + BLK - 1) / BLK;
        int sgrid = (int)(((long long)NNZ_CNT * 16 + BLK - 1) / BLK);
        zero_slot1_k<<<zgrid, BLK, 0, stream>>>(out);
        scatter_fb_k<<<sgrid, BLK, 0, stream>>>(adj_rows, adj_cols, adj_vals,
                                                user_emb, item_emb, out + OFF_STACK + 64);
        scatter_fb_k<<<sgrid, BLK, 0, stream>>>(radj_rows, radj_cols, radj_vals,
                                                user_emb, item_emb, out + OFF_PATH + 64);
        finalize_k<<<zgrid, BLK, 0, stream>>>(user_emb, item_emb, out);
    }
}

// Round 5
// 648.671 us; speedup vs baseline: 1.7905x; 1.0543x over previous
//
#include <hip/hip_runtime.h>

#define U_CNT 100000
#define I_CNT 50000
#define N_CNT 150000
#define D_CNT 64
#define NNZ_CNT 1000000

#define OFF_ITEM   6400000LL
#define OFF_STACK  9600000LL
#define OFF_PATH   48000000LL

#define RPB   64      // rows per bucket
#define NBUK  2344    // ceil(150000/64)
#define NREP  8       // counter replicas (cuts same-line atomic contention 8x)
#define SPR   8       // counter pad stride (ints) -> 32B per counter
#define CAP   1024    // edges per bspmm chunk
#define EBUF  1536    // CAP + 64*7 pad slots (row runs padded to multiple of 8)

// cnt_r layout: cnt_r[((m*NREP + rep)*NBUK + bucket)*SPR]
// off  layout: off[m*(NBUK+1) + bucket], off[m*(NBUK+1)+NBUK] = NNZ (sentinel)

// ---------------- bucket-CSR build ----------------

__global__ void bzero_k(int* __restrict__ cnt_r) {
    int i = blockIdx.x * blockDim.x + threadIdx.x;
    if (i < 2 * NREP * NBUK * SPR) cnt_r[i] = 0;
}

// 250K threads/matrix, int4 loads, 4 independent atomics into this block's replica.
__global__ __launch_bounds__(256) void bhist_k(const int* __restrict__ arows,
                                               const int* __restrict__ rrows,
                                               int* __restrict__ cnt_r) {
    int gid = blockIdx.x * 256 + threadIdx.x;
    if (gid >= NNZ_CNT / 4) return;
    const int4* rows = (const int4*)(blockIdx.y ? rrows : arows);
    int rep = blockIdx.x & (NREP - 1);
    int* c = cnt_r + (size_t)(blockIdx.y * NREP + rep) * NBUK * SPR;
    int4 r = rows[gid];
    atomicAdd(&c[(r.x >> 6) * SPR], 1);
    atomicAdd(&c[(r.y >> 6) * SPR], 1);
    atomicAdd(&c[(r.z >> 6) * SPR], 1);
    atomicAdd(&c[(r.w >> 6) * SPR], 1);
}

// per matrix: bucket totals = sum over replicas; exclusive scan over buckets;
// rewrite cnt_r in place as per-replica cursors (disjoint slices per bucket).
__global__ __launch_bounds__(1024) void bscan_k(int* __restrict__ cnt_r,
                                                int* __restrict__ off) {
    __shared__ int s[1024];
    const int m = blockIdx.x;
    const int t = threadIdx.x;
    int base = t * 3;
    int cv[3][NREP];
    int tot[3];
    int run = 0;
    #pragma unroll
    for (int k = 0; k < 3; ++k) {
        tot[k] = 0;
        if (base + k < NBUK) {
            #pragma unroll
            for (int rep = 0; rep < NREP; ++rep) {
                cv[k][rep] = cnt_r[((size_t)(m * NREP + rep) * NBUK + base + k) * SPR];
                tot[k] += cv[k][rep];
            }
        }
        run += tot[k];
    }
    s[t] = run;
    __syncthreads();
    for (int d = 1; d < 1024; d <<= 1) {
        int a = (t >= d) ? s[t - d] : 0;
        __syncthreads();
        s[t] += a;
        __syncthreads();
    }
    int pre = s[t] - run;   // exclusive prefix
    #pragma unroll
    for (int k = 0; k < 3; ++k) {
        if (base + k < NBUK) {
            off[m * (NBUK + 1) + base + k] = pre;
            int cur = pre;
            #pragma unroll
            for (int rep = 0; rep < NREP; ++rep) {
                cnt_r[((size_t)(m * NREP + rep) * NBUK + base + k) * SPR] = cur;
                cur += cv[k][rep];
            }
        }
        pre += tot[k];
    }
    if (t == 0) off[m * (NBUK + 1) + NBUK] = NNZ_CNT;
}

// one-pass scatter: int4 loads, 4 independent cursor atomics (replica-local slice).
__global__ __launch_bounds__(256) void bscat_k(
    const int* __restrict__ arows, const int* __restrict__ acols, const float* __restrict__ avals,
    const int* __restrict__ rrows, const int* __restrict__ rcols, const float* __restrict__ rvals,
    int* __restrict__ cur_r, int2* __restrict__ ed) {
    int gid = blockIdx.x * 256 + threadIdx.x;
    if (gid >= NNZ_CNT / 4) return;
    const int4*   rows = (const int4*)(blockIdx.y ? rrows : arows);
    const int4*   cols = (const int4*)(blockIdx.y ? rcols : acols);
    const float4* vals = (const float4*)(blockIdx.y ? rvals : avals);
    int rep = blockIdx.x & (NREP - 1);
    int*  cu = cur_r + (size_t)(blockIdx.y * NREP + rep) * NBUK * SPR;
    int2* e  = ed + (size_t)blockIdx.y * NNZ_CNT;
    int4 r = rows[gid];
    int4 c = cols[gid];
    float4 v = vals[gid];
    int p0 = atomicAdd(&cu[(r.x >> 6) * SPR], 1);
    int p1 = atomicAdd(&cu[(r.y >> 6) * SPR], 1);
    int p2 = atomicAdd(&cu[(r.z >> 6) * SPR], 1);
    int p3 = atomicAdd(&cu[(r.w >> 6) * SPR], 1);
    e[p0] = make_int2(((r.x & 63) << 18) | c.x, __float_as_int(v.x));
    e[p1] = make_int2(((r.y & 63) << 18) | c.y, __float_as_int(v.y));
    e[p2] = make_int2(((r.z & 63) << 18) | c.z, __float_as_int(v.z));
    e[p3] = make_int2(((r.w & 63) << 18) | c.w, __float_as_int(v.w));
}

// block per bucket: LDS counting sort (int atomics only), row runs padded to x8,
// then each wave owns 16 rows; rows processed in PAIRS -> 16 independent 256B
// gathers in flight before the first FMA (round-4 had 8). No float atomics.
__global__ __launch_bounds__(256) void bspmm_k(
    const int* __restrict__ off,
    const int2* __restrict__ ed,
    const float* __restrict__ user_emb, const float* __restrict__ item_emb,
    float* __restrict__ out) {
    __shared__ int2 ebuf[EBUF];
    __shared__ int rcnt[64];
    __shared__ int rcur[64];
    __shared__ int roff[65];
    const int which = blockIdx.y;
    const int b = blockIdx.x;
    const int2* e = ed + (size_t)which * NNZ_CNT;
    const int o = off[which * (NBUK + 1) + b];
    const int c = off[which * (NBUK + 1) + b + 1] - o;
    const int t = threadIdx.x, wid = t >> 6, lane = t & 63;
    const bool multi = (c > CAP);
    const int nchunk = multi ? (c + CAP - 1) / CAP : 1;

    for (int ci = 0; ci < nchunk; ++ci) {
        const int s = ci * CAP;
        int cc = c - s;
        if (cc > CAP) cc = CAP;
        if (cc < 0) cc = 0;
        for (int i = t; i < EBUF; i += 256) ebuf[i] = make_int2(0, 0);
        if (t < 64) rcnt[t] = 0;
        __syncthreads();
        int2 er[4];
        #pragma unroll
        for (int k = 0; k < 4; ++k) {
            int i = t + k * 256;
            er[k] = (i < cc) ? e[o + s + i] : make_int2(-1, 0);
        }
        #pragma unroll
        for (int k = 0; k < 4; ++k)
            if (er[k].x >= 0) atomicAdd(&rcnt[er[k].x >> 18], 1);
        __syncthreads();
        if (t < 64) {
            int pv = (rcnt[t] + 7) & ~7;     // pad row run to multiple of 8
            int incl = pv;
            #pragma unroll
            for (int d = 1; d < 64; d <<= 1) {
                int u = __shfl_up(incl, d);
                if (lane >= d) incl += u;
            }
            roff[t + 1] = incl;
            if (t == 0) roff[0] = 0;
            rcur[t] = incl - pv;
        }
        __syncthreads();
        #pragma unroll
        for (int k = 0; k < 4; ++k)
            if (er[k].x >= 0) {
                int p = atomicAdd(&rcur[er[k].x >> 18], 1);
                ebuf[p] = er[k];
            }
        __syncthreads();
        // each wave: 16 rows, processed two at a time (double MLP)
        for (int rr = 0; rr < 16; rr += 2) {
            const int rA = wid * 16 + rr, rB = rA + 1;
            const int jA0 = roff[rA], lA = roff[rA + 1] - jA0;
            const int jB0 = roff[rB], lB = roff[rB + 1] - jB0;
            const int L = lA > lB ? lA : lB;
            float accA = 0.f, accB = 0.f;
            for (int j = 0; j < L; j += 8) {
                const bool doA = j < lA, doB = j < lB;   // wave-uniform
                int2 EA[8], EB[8];
                if (doA) {
                    #pragma unroll
                    for (int k = 0; k < 8; ++k) EA[k] = ebuf[jA0 + j + k];
                }
                if (doB) {
                    #pragma unroll
                    for (int k = 0; k < 8; ++k) EB[k] = ebuf[jB0 + j + k];
                }
                float gA[8], gB[8];
                if (doA) {
                    #pragma unroll
                    for (int k = 0; k < 8; ++k) {
                        int col = EA[k].x & 0x3FFFF;
                        const float* src = (col < U_CNT) ? (user_emb + (size_t)col * D_CNT)
                                                         : (item_emb + (size_t)(col - U_CNT) * D_CNT);
                        gA[k] = src[lane];
                    }
                }
                if (doB) {
                    #pragma unroll
                    for (int k = 0; k < 8; ++k) {
                        int col = EB[k].x & 0x3FFFF;
                        const float* src = (col < U_CNT) ? (user_emb + (size_t)col * D_CNT)
                                                         : (item_emb + (size_t)(col - U_CNT) * D_CNT);
                        gB[k] = src[lane];
                    }
                }
                if (doA) {
                    #pragma unroll
                    for (int k = 0; k < 8; ++k) accA = fmaf(__int_as_float(EA[k].y), gA[k], accA);
                }
                if (doB) {
                    #pragma unroll
                    for (int k = 0; k < 8; ++k) accB = fmaf(__int_as_float(EB[k].y), gB[k], accB);
                }
            }
            #pragma unroll
            for (int h = 0; h < 2; ++h) {
                const int row = b * RPB + (h ? rB : rA);
                const float acc = h ? accB : accA;
                if (row >= N_CNT) continue;
                const long long rb = (which ? OFF_PATH : OFF_STACK) + (long long)row * 256;
                if (!multi) {
                    const float* esrc = (row < U_CNT) ? (user_emb + (size_t)row * D_CNT)
                                                      : (item_emb + (size_t)(row - U_CNT) * D_CNT);
                    float eg = esrc[lane];
                    out[rb + lane]       = eg;
                    out[rb + 64 + lane]  = acc;
                    out[rb + 128 + lane] = acc;
                    out[rb + 192 + lane] = acc;
                    if (which == 0) {
                        float mv = 0.25f * eg + 0.75f * acc;
                        long long mb = (row < U_CNT) ? (long long)row * D_CNT
                                                     : OFF_ITEM + (long long)(row - U_CNT) * D_CNT;
                        out[mb + lane] = mv;
                    }
                } else {
                    float prev = (ci == 0) ? 0.f : out[rb + 64 + lane];
                    out[rb + 64 + lane] = prev + acc;
                }
            }
        }
        __syncthreads();
    }
    if (multi) {
        for (int rr = 0; rr < 16; ++rr) {
            const int r = wid * 16 + rr;
            const int row = b * RPB + r;
            if (row >= N_CNT) continue;
            const long long rb = (which ? OFF_PATH : OFF_STACK) + (long long)row * 256;
            float acc = out[rb + 64 + lane];
            const float* esrc = (row < U_CNT) ? (user_emb + (size_t)row * D_CNT)
                                              : (item_emb + (size_t)(row - U_CNT) * D_CNT);
            float eg = esrc[lane];
            out[rb + lane]       = eg;
            out[rb + 128 + lane] = acc;
            out[rb + 192 + lane] = acc;
            if (which == 0) {
                float mv = 0.25f * eg + 0.75f * acc;
                long long mb = (row < U_CNT) ? (long long)row * D_CNT
                                             : OFF_ITEM + (long long)(row - U_CNT) * D_CNT;
                out[mb + lane] = mv;
            }
        }
    }
}

// ---------------- fallback atomic path (ws too small) ----------------

__global__ void zero_slot1_k(float* __restrict__ out) {
    int t = blockIdx.x * blockDim.x + threadIdx.x;
    if (t >= N_CNT * 16) return;
    int n = t >> 4, q = t & 15;
    long long off = (long long)n * 256 + 64 + (long long)q * 4;
    float4 z = make_float4(0.f, 0.f, 0.f, 0.f);
    *(float4*)(out + OFF_STACK + off) = z;
    *(float4*)(out + OFF_PATH  + off) = z;
}

__global__ void scatter_fb_k(const int* __restrict__ rows, const int* __restrict__ cols,
                             const float* __restrict__ vals,
                             const float* __restrict__ user_emb, const float* __restrict__ item_emb,
                             float* __restrict__ acc) {
    long long t = (long long)blockIdx.x * blockDim.x + threadIdx.x;
    int e = (int)(t >> 4);
    if (e >= NNZ_CNT) return;
    int q = (int)(t & 15);
    int r = rows[e];
    int c = cols[e];
    float v = vals[e];
    const float* src = (c < U_CNT) ? (user_emb + (long long)c * D_CNT)
                                   : (item_emb + (long long)(c - U_CNT) * D_CNT);
    float4 x = *(const float4*)(src + q * 4);
    float* dst = acc + (long long)r * 256 + q * 4;
    atomicAdd(dst + 0, v * x.x);
    atomicAdd(dst + 1, v * x.y);
    atomicAdd(dst + 2, v * x.z);
    atomicAdd(dst + 3, v * x.w);
}

__global__ void finalize_k(const float* __restrict__ user_emb,
                           const float* __restrict__ item_emb,
                           float* __restrict__ out) {
    int t = blockIdx.x * blockDim.x + threadIdx.x;
    if (t >= N_CNT * 16) return;
    int n = t >> 4, q = t & 15;
    const float* src = (n < U_CNT) ? (user_emb + (long long)n * D_CNT)
                                   : (item_emb + (long long)(n - U_CNT) * D_CNT);
    float4 e4 = *(const float4*)(src + q * 4);
    float* st = out + OFF_STACK + (long long)n * 256;
    float* pt = out + OFF_PATH  + (long long)n * 256;
    float4 a4 = *(const float4*)(st + 64 + q * 4);
    float4 r4 = *(const float4*)(pt + 64 + q * 4);
    float4 m4 = make_float4(0.25f * e4.x + 0.75f * a4.x, 0.25f * e4.y + 0.75f * a4.y,
                            0.25f * e4.z + 0.75f * a4.z, 0.25f * e4.w + 0.75f * a4.w);
    *(float4*)(st + q * 4)       = e4;
    *(float4*)(st + 128 + q * 4) = a4;
    *(float4*)(st + 192 + q * 4) = a4;
    *(float4*)(pt + q * 4)       = e4;
    *(float4*)(pt + 128 + q * 4) = r4;
    *(float4*)(pt + 192 + q * 4) = r4;
    float* md = (n < U_CNT) ? (out + (long long)n * D_CNT)
                            : (out + OFF_ITEM + (long long)(n - U_CNT) * D_CNT);
    *(float4*)(md + q * 4) = m4;
}

extern "C" void kernel_launch(void* const* d_in, const int* in_sizes, int n_in,
                              void* d_out, int out_size, void* d_ws, size_t ws_size,
                              hipStream_t stream) {
    const float* user_emb  = (const float*)d_in[0];
    const float* item_emb  = (const float*)d_in[1];
    const int*   adj_rows  = (const int*)d_in[2];
    const int*   adj_cols  = (const int*)d_in[3];
    const float* adj_vals  = (const float*)d_in[4];
    const int*   radj_rows = (const int*)d_in[5];
    const int*   radj_cols = (const int*)d_in[6];
    const float* radj_vals = (const float*)d_in[7];
    float* out = (float*)d_out;
    const int BLK = 256;

    // ws layout (ints): cnt_r[2*NREP*NBUK*SPR] (counts -> cursors in place),
    //                   off[2*(NBUK+1)], then int2 ed[2*NNZ]
    size_t cnt_sz = (size_t)2 * NREP * NBUK * SPR;
    size_t off_sz = (size_t)2 * (NBUK + 1);
    size_t need = (cnt_sz + off_sz) * 4 + (size_t)2 * NNZ_CNT * 8;
    if (ws_size >= need) {
        int* cnt_r = (int*)d_ws;
        int* off   = cnt_r + cnt_sz;
        int2* ed   = (int2*)(off + off_sz);

        bzero_k<<<(int)((cnt_sz + BLK - 1) / BLK), BLK, 0, stream>>>(cnt_r);
        int vgrid = (NNZ_CNT / 4 + 255) / 256;
        bhist_k<<<dim3(vgrid, 2), 256, 0, stream>>>(adj_rows, radj_rows, cnt_r);
        bscan_k<<<2, 1024, 0, stream>>>(cnt_r, off);
        bscat_k<<<dim3(vgrid, 2), 256, 0, stream>>>(adj_rows, adj_cols, adj_vals,
                                                    radj_rows, radj_cols, radj_vals,
                                                    cnt_r, ed);
        bspmm_k<<<dim3(NBUK, 2), 256, 0, stream>>>(off, ed, user_emb, item_emb, out);
    } else {
        int zgrid = (N_CNT * 16 + BLK - 1) / BLK;
        int sgrid = (int)(((long long)NNZ_CNT * 16 + BLK - 1) / BLK);
        zero_slot1_k<<<zgrid, BLK, 0, stream>>>(out);
        scatter_fb_k<<<sgrid, BLK, 0, stream>>>(adj_rows, adj_cols, adj_vals,
                                                user_emb, item_emb, out + OFF_STACK + 64);
        scatter_fb_k<<<sgrid, BLK, 0, stream>>>(radj_rows, radj_cols, radj_vals,
                                                user_emb, item_emb, out + OFF_PATH + 64);
        finalize_k<<<zgrid, BLK, 0, stream>>>(user_emb, item_emb, out);
    }
}